// Round 6
// baseline (102.274 us; speedup 1.0000x reference)
//
#include <hip/hip_runtime.h>
#include <hip/hip_bf16.h>

// dce_loss: out = concat(centers, sigma, -dist)
// -dist[b,i] = sum_k A[b,k]*W[i,k] + cn[i],  A=[bf16(x^2)|bf16(x)], W=[-sigma|2*sigma*c]
// GEMM 256x256, BK=64, 8 waves, mfma 32x32x16. A: ring-3 LDS (96KB), stage
// dist 2 tiles, slot^=(row&7). B: ring-3 half-tile LDS (48KB), slot=(l+(r>>1))&3.
// 2 phases/tile; per phase: {stages + next-phase ds_read prefetch} | SB |
// setprio(1) 16 MFMA setprio(0) | vmcnt(6) | barrier.  sched_barrier pins the
// reads ABOVE the MFMA cluster so LDS pipe overlaps MFMA pipe.

#define B_SZ 8192
#define C_SZ 2048
#define D_SZ 1024
#define K2   2048

typedef __attribute__((ext_vector_type(4))) float f32x4;
typedef __attribute__((ext_vector_type(16))) float f32x16;
typedef __attribute__((ext_vector_type(8))) short bf16x8;

static __device__ __forceinline__ unsigned short f2bf(float f) {
  union { float f; unsigned int u; } v; v.f = f;
  unsigned int r = v.u + 0x7fffu + ((v.u >> 16) & 1u);   // RNE, finite inputs
  return (unsigned short)(r >> 16);
}

// ---- preprocess: A = [bf16(x^2) | bf16(x)] ----------------------------------
__global__ __launch_bounds__(256) void build_a(const float* __restrict__ x,
                                               unsigned short* __restrict__ Aop) {
  const long t = (long)blockIdx.x * 256 + threadIdx.x;
  const long e = t * 8;
  const long b = e >> 10;
  const int  d = (int)(e & 1023);
  const float4* xv = (const float4*)x;
  float4 v0 = xv[2 * t], v1 = xv[2 * t + 1];
  float vs[8] = {v0.x, v0.y, v0.z, v0.w, v1.x, v1.y, v1.z, v1.w};
  unsigned short sq[8] __attribute__((aligned(16)));
  unsigned short rw[8] __attribute__((aligned(16)));
#pragma unroll
  for (int j = 0; j < 8; ++j) {
    rw[j] = f2bf(vs[j]);
    sq[j] = f2bf(vs[j] * vs[j]);
  }
  *(uint4*)(Aop + b * K2 + d)        = *(uint4*)sq;
  *(uint4*)(Aop + b * K2 + D_SZ + d) = *(uint4*)rw;
}

// ---- fused: output copies of centers/sigma + W build + cn reduction ---------
__global__ __launch_bounds__(128) void prep_w(const float* __restrict__ centers,
                                              const float* __restrict__ sigma,
                                              float* __restrict__ out_centers,
                                              float* __restrict__ out_sigma,
                                              unsigned short* __restrict__ Wop,
                                              float* __restrict__ cn) {
  const int i = blockIdx.x;
  const int t = threadIdx.x;
  const long base = (long)i * D_SZ;
  const float4* cv = (const float4*)(centers + base);
  const float4* sv = (const float4*)(sigma + base);
  float4 c0 = cv[2 * t], c1 = cv[2 * t + 1];
  float4 s0 = sv[2 * t], s1 = sv[2 * t + 1];
  ((float4*)(out_centers + base))[2 * t]     = c0;
  ((float4*)(out_centers + base))[2 * t + 1] = c1;
  ((float4*)(out_sigma + base))[2 * t]       = s0;
  ((float4*)(out_sigma + base))[2 * t + 1]   = s1;
  float cs[8] = {c0.x, c0.y, c0.z, c0.w, c1.x, c1.y, c1.z, c1.w};
  float ss[8] = {s0.x, s0.y, s0.z, s0.w, s1.x, s1.y, s1.z, s1.w};
  unsigned short w1[8] __attribute__((aligned(16)));
  unsigned short w2[8] __attribute__((aligned(16)));
  float p = 0.0f;
#pragma unroll
  for (int j = 0; j < 8; ++j) {
    w1[j] = f2bf(-ss[j]);
    w2[j] = f2bf(2.0f * ss[j] * cs[j]);
    p += ss[j] * cs[j] * cs[j];
  }
  *(uint4*)(Wop + (long)i * K2 + t * 8)        = *(uint4*)w1;
  *(uint4*)(Wop + (long)i * K2 + D_SZ + t * 8) = *(uint4*)w2;
#pragma unroll
  for (int off = 32; off > 0; off >>= 1) p += __shfl_down(p, off, 64);
  __shared__ float red[2];
  if ((t & 63) == 0) red[t >> 6] = p;
  __syncthreads();
  if (t == 0) cn[i] = -(red[0] + red[1]);
}

// ---- GEMM -------------------------------------------------------------------
#define VM6()  asm volatile("s_waitcnt vmcnt(6)" ::: "memory")
#define VM2()  asm volatile("s_waitcnt vmcnt(2)" ::: "memory")
#define VM0()  asm volatile("s_waitcnt vmcnt(0)" ::: "memory")
#define NOW()  ((void)0)
#define SB()   __builtin_amdgcn_sched_barrier(0)
#define BAR()  __builtin_amdgcn_s_barrier()

// A tile KT -> ring buf C (4 loads: 64 rows each)
#define STAGE_A(C, KT)                                                          \
  do {                                                                          \
    __builtin_amdgcn_global_load_lds(                                           \
        (__attribute__((address_space(1))) void*)(aS + 0 * 64 * (long)K2 + (long)(KT) * 64), \
        (__attribute__((address_space(3))) void*)(&As[C][0 * 4096 + dstE]), 16, 0, 0);       \
    __builtin_amdgcn_global_load_lds(                                           \
        (__attribute__((address_space(1))) void*)(aS + 1 * 64 * (long)K2 + (long)(KT) * 64), \
        (__attribute__((address_space(3))) void*)(&As[C][1 * 4096 + dstE]), 16, 0, 0);       \
    __builtin_amdgcn_global_load_lds(                                           \
        (__attribute__((address_space(1))) void*)(aS + 2 * 64 * (long)K2 + (long)(KT) * 64), \
        (__attribute__((address_space(3))) void*)(&As[C][2 * 4096 + dstE]), 16, 0, 0);       \
    __builtin_amdgcn_global_load_lds(                                           \
        (__attribute__((address_space(1))) void*)(aS + 3 * 64 * (long)K2 + (long)(KT) * 64), \
        (__attribute__((address_space(3))) void*)(&As[C][3 * 4096 + dstE]), 16, 0, 0);       \
  } while (0)

// B half (tile KT, k-half KK) -> half-ring buf C (2 loads: 128 rows each)
#define STAGE_B(C, KT, KK)                                                      \
  do {                                                                          \
    __builtin_amdgcn_global_load_lds(                                           \
        (__attribute__((address_space(1))) void*)(bS + 0 * 128 * (long)K2 + (long)(KT) * 64 + (KK) * 32), \
        (__attribute__((address_space(3))) void*)(&Bs[C][0 * 4096 + dstE]), 16, 0, 0);                    \
    __builtin_amdgcn_global_load_lds(                                           \
        (__attribute__((address_space(1))) void*)(bS + 1 * 128 * (long)K2 + (long)(KT) * 64 + (KK) * 32), \
        (__attribute__((address_space(3))) void*)(&Bs[C][1 * 4096 + dstE]), 16, 0, 0);                    \
  } while (0)

// fragment reads (swizzled, bank-uniform)
// A: row = wr*128 + MI*32 + (lane&31), logical slot = KS*2 + (lane>>5)
#define LDA(BUF, KS, MI) (*(const bf16x8*)(&As[BUF][aBase + (MI) * 2048 + sA##KS]))
// B: row = wc*64 + NI*32 + (lane&31), logical slot (in half) = J*2 + (lane>>5)
#define LDB(BUF, J, NI)  (*(const bf16x8*)(&Bs[BUF][bBase + (NI) * 1024 + sB##J]))

#define MFMA3216 __builtin_amdgcn_mfma_f32_32x32x16_bf16

// 8 MFMA: one k-step, 4 mi x 2 ni  (acc index = mi*2 + ni)
#define MM8(A0, A1, A2, A3, B0, B1)        \
  ac0 = MFMA3216(A0, B0, ac0, 0, 0, 0);    \
  ac1 = MFMA3216(A0, B1, ac1, 0, 0, 0);    \
  ac2 = MFMA3216(A1, B0, ac2, 0, 0, 0);    \
  ac3 = MFMA3216(A1, B1, ac3, 0, 0, 0);    \
  ac4 = MFMA3216(A2, B0, ac4, 0, 0, 0);    \
  ac5 = MFMA3216(A2, B1, ac5, 0, 0, 0);    \
  ac6 = MFMA3216(A3, B0, ac6, 0, 0, 0);    \
  ac7 = MFMA3216(A3, B1, ac7, 0, 0, 0);

// One K-tile U from A-buf AC / B-half-bufs (P1 = B(U,h1); P2 = B(U+1,h0)).
// Phase A (ksteps 0,1): stage B(U+1,h1)->BS0 + A(U+2)->AST; prefetch aQ/bQ;
//   SB; MFMA on aP/bP; vmcnt; BAR.
// Phase B (ksteps 2,3): stage B(U+2,h0)->BS1; prefetch aP/bP from AN/P2;
//   SB; MFMA on aQ/bQ; vmcnt; BAR.
#define TILE(AC, AN, AST, P1, P2, BS0, BS1, U, STGA, SB0_, SB1_, W0, W1, PRE)  \
  { /* phase A */                                                              \
    if (SB0_) STAGE_B(BS0, (U) + 1, 1);                                        \
    if (STGA) STAGE_A(AST, (U) + 2);                                           \
    aQ0 = LDA(AC, 2, 0); aQ1 = LDA(AC, 2, 1);                                  \
    aQ2 = LDA(AC, 2, 2); aQ3 = LDA(AC, 2, 3);                                  \
    aQ4 = LDA(AC, 3, 0); aQ5 = LDA(AC, 3, 1);                                  \
    aQ6 = LDA(AC, 3, 2); aQ7 = LDA(AC, 3, 3);                                  \
    bQ0 = LDB(P1, 0, 0); bQ1 = LDB(P1, 0, 1);                                  \
    bQ2 = LDB(P1, 1, 0); bQ3 = LDB(P1, 1, 1);                                  \
    SB();                                                                      \
    __builtin_amdgcn_s_setprio(1);                                             \
    MM8(aP0, aP1, aP2, aP3, bP0, bP1)                                          \
    MM8(aP4, aP5, aP6, aP7, bP2, bP3)                                          \
    __builtin_amdgcn_s_setprio(0);                                             \
    SB(); W0(); SB(); BAR();                                                   \
  }                                                                            \
  { /* phase B */                                                              \
    if (SB1_) STAGE_B(BS1, (U) + 2, 0);                                        \
    if (PRE) {                                                                 \
      aP0 = LDA(AN, 0, 0); aP1 = LDA(AN, 0, 1);                                \
      aP2 = LDA(AN, 0, 2); aP3 = LDA(AN, 0, 3);                                \
      aP4 = LDA(AN, 1, 0); aP5 = LDA(AN, 1, 1);                                \
      aP6 = LDA(AN, 1, 2); aP7 = LDA(AN, 1, 3);                                \
      bP0 = LDB(P2, 0, 0); bP1 = LDB(P2, 0, 1);                                \
      bP2 = LDB(P2, 1, 0); bP3 = LDB(P2, 1, 1);                                \
    }                                                                          \
    SB();                                                                      \
    __builtin_amdgcn_s_setprio(1);                                             \
    MM8(aQ0, aQ1, aQ2, aQ3, bQ0, bQ1)                                          \
    MM8(aQ4, aQ5, aQ6, aQ7, bQ2, bQ3)                                          \
    __builtin_amdgcn_s_setprio(0);                                             \
    SB(); W1(); SB(); BAR();                                                   \
  }

#define Z16(V)                                                                 \
  _Pragma("unroll") for (int z_ = 0; z_ < 16; ++z_) V[z_] = 0.0f;

// epilogue per fragment: col = lane&31 (+ni*32), row = (rg&3)+8*(rg>>2)+4*(lane>>5)
#define EPI(ACF, MI, NI)                                                       \
  {                                                                            \
    const long col = colBase + wc * 64 + (NI) * 32 + (lane & 31);              \
    const float c = cn[col];                                                   \
    float* o = out + (rowBase + wr * 128 + (MI) * 32 + 4 * q5) * (long)C_SZ + col; \
    _Pragma("unroll") for (int rg = 0; rg < 16; ++rg)                          \
        o[(long)((rg & 3) + 8 * (rg >> 2)) * C_SZ] = ACF[rg] + c;              \
  }

__global__ __launch_bounds__(512, 2) void gemm256(const unsigned short* __restrict__ A,
                                                  const unsigned short* __restrict__ W,
                                                  const float* __restrict__ cn,
                                                  float* __restrict__ out) {
  // A: ring-3 [3][256 rows][64 k], phys 16B-slot = logical ^ (row&7)   (96KB)
  // B: half-ring-3 [3][256 rows][32 k], phys slot = (logical + (row>>1)) & 3 (48KB)
  __shared__ __attribute__((aligned(16))) unsigned short As[3][16384];
  __shared__ __attribute__((aligned(16))) unsigned short Bs[3][8192];

  const int tid  = threadIdx.x;
  const int lane = tid & 63;
  const int wave = tid >> 6;
  const int wr = wave >> 2;              // 0..1 -> 128-row half of M
  const int wc = wave & 3;               // 0..3 -> 64-row slice of N

  // XCD-aware block swizzle: xcd owns 4 m-panels x 8 n-tiles
  const int bid = blockIdx.x;
  const int xcd = bid & 7, idx = bid >> 3;
  const long rowBase = (long)(xcd * 4 + (idx >> 3)) * 256;
  const long colBase = (long)(idx & 7) * 256;

  // A staging: rows (tid>>3)+{0,64,128,192}; phys slot tid&7 <- logical (tid&7)^(row&7)
  const int sr = tid >> 3;
  const int sl = (tid & 7) ^ (sr & 7);
  const unsigned short* aS = A + (rowBase + sr) * (long)K2 + sl * 8;
  // B staging: rows (tid>>2)+{0,128}; phys slot tid&3 <- logical ((tid&3)-(row>>1))&3
  const int br = tid >> 2;
  const int bl = ((tid & 3) - (tid >> 3)) & 3;
  const unsigned short* bS = W + (colBase + br) * (long)K2 + bl * 8;
  const int dstE = tid * 8;

  // fragment read bases
  const int l31 = lane & 31, l7 = lane & 7, q5 = lane >> 5;
  const int rp  = (lane >> 1) & 3;
  const int aBase = (wr * 128 + l31) * 64;
  const int bBase = (wc * 64 + l31) * 32;
  const int sA0 = ((0 + q5) ^ l7) * 8;
  const int sA1 = ((2 + q5) ^ l7) * 8;
  const int sA2 = ((4 + q5) ^ l7) * 8;
  const int sA3 = ((6 + q5) ^ l7) * 8;
  const int sB0 = ((q5 + rp) & 3) * 8;
  const int sB1 = ((2 + q5 + rp) & 3) * 8;

  f32x16 ac0, ac1, ac2, ac3, ac4, ac5, ac6, ac7;
  Z16(ac0) Z16(ac1) Z16(ac2) Z16(ac3) Z16(ac4) Z16(ac5) Z16(ac6) Z16(ac7)

  bf16x8 aP0, aP1, aP2, aP3, aP4, aP5, aP6, aP7;
  bf16x8 aQ0, aQ1, aQ2, aQ3, aQ4, aQ5, aQ6, aQ7;
  bf16x8 bP0, bP1, bP2, bP3, bQ0, bQ1, bQ2, bQ3;

  // prologue: A(0)->0, Bh0->0, Bh1->1, A(1)->1, Bh2->2  (14 loads)
  STAGE_A(0, 0);
  STAGE_B(0, 0, 0);
  STAGE_B(1, 0, 1);
  STAGE_A(1, 1);
  STAGE_B(2, 1, 0);
  VM6(); SB(); BAR();   // A0,B(0,h0),B(0,h1) landed; A1,B(1,h0) in flight
  // preload tile-0 phase-A fragments (ksteps 0,1)
  aP0 = LDA(0, 0, 0); aP1 = LDA(0, 0, 1); aP2 = LDA(0, 0, 2); aP3 = LDA(0, 0, 3);
  aP4 = LDA(0, 1, 0); aP5 = LDA(0, 1, 1); aP6 = LDA(0, 1, 2); aP7 = LDA(0, 1, 3);
  bP0 = LDB(0, 0, 0); bP1 = LDB(0, 0, 1); bP2 = LDB(0, 1, 0); bP3 = LDB(0, 1, 1);

  // tiles 0..29: period 3 (A buf = t%3; B half h -> buf h%3)
#pragma unroll 1
  for (int u = 0; u < 30; u += 3) {
    TILE(0, 1, 2, 1, 2, 0, 1, u + 0, 1, 1, 1, VM6, VM6, 1);
    TILE(1, 2, 0, 0, 1, 2, 0, u + 1, 1, 1, 1, VM6, VM6, 1);
    TILE(2, 0, 1, 2, 0, 1, 2, u + 2, 1, 1, 1, VM6, VM6, 1);
  }
  // tail: tile 30 (stage only B(31,h1)), tile 31 (no stages, no final prefetch)
  TILE(0, 1, 2, 1, 2, 0, 1, 30, 0, 1, 0, VM2, VM0, 1);
  TILE(1, 2, 0, 0, 1, 2, 0, 31, 0, 0, 0, NOW, NOW, 0);

  // epilogue: 32x32 C/D layout col=lane&31, row=(rg&3)+8*(rg>>2)+4*(lane>>5)
  EPI(ac0, 0, 0) EPI(ac1, 0, 1)
  EPI(ac2, 1, 0) EPI(ac3, 1, 1)
  EPI(ac4, 2, 0) EPI(ac5, 2, 1)
  EPI(ac6, 3, 0) EPI(ac7, 3, 1)
}

extern "C" void kernel_launch(void* const* d_in, const int* in_sizes, int n_in,
                              void* d_out, int out_size, void* d_ws, size_t ws_size,
                              hipStream_t stream) {
  const float* x       = (const float*)d_in[0];
  const float* centers = (const float*)d_in[1];
  const float* sigma   = (const float*)d_in[2];
  float* out = (float*)d_out;

  unsigned short* Aop = (unsigned short*)d_ws;            // 8192*2048 bf16
  unsigned short* Wop = Aop + (long)B_SZ * K2;            // 2048*2048 bf16
  float* cnp = (float*)(Wop + (long)C_SZ * K2);           // 2048 f32

  build_a<<<B_SZ * D_SZ / 8 / 256, 256, 0, stream>>>(x, Aop);
  prep_w<<<C_SZ, 128, 0, stream>>>(centers, sigma,
                                   out, out + (size_t)C_SZ * D_SZ, Wop, cnp);

  float* out2 = out + (size_t)2 * C_SZ * D_SZ;
  gemm256<<<256, 512, 0, stream>>>(Aop, Wop, cnp, out2);
}

// Round 7
// 96.672 us; speedup vs baseline: 1.0580x; 1.0580x over previous
//
#include <hip/hip_runtime.h>
#include <hip/hip_bf16.h>

// dce_loss: out = concat(centers, sigma, -dist)
// -dist[b,i] = sum_k A[b,k]*W[i,k] + cn[i],  A=[bf16(x^2)|bf16(x)], W=[-sigma|2*sigma*c]
// GEMM 256x256, BK=64, 8 waves, mfma 16x16x32. A: ring-3 LDS (96KB), stage
// dist 2 tiles, slot^=(row&7). B: ring-3 half-tile LDS (48KB), slot=(q+(row>>1))&3.
// 2 phases/tile, 32 MFMA each; per phase: {stages + next-phase ds_read prefetch}
// | sched_barrier | setprio(1) MFMA setprio(0) | vmcnt(6) | barrier.
// sched_barrier pins reads ABOVE the MFMA cluster -> LDS pipe overlaps MFMA pipe.

#define B_SZ 8192
#define C_SZ 2048
#define D_SZ 1024
#define K2   2048

typedef __attribute__((ext_vector_type(4))) float f32x4;
typedef __attribute__((ext_vector_type(8))) short bf16x8;

static __device__ __forceinline__ unsigned short f2bf(float f) {
  union { float f; unsigned int u; } v; v.f = f;
  unsigned int r = v.u + 0x7fffu + ((v.u >> 16) & 1u);   // RNE, finite inputs
  return (unsigned short)(r >> 16);
}

// ---- preprocess: A = [bf16(x^2) | bf16(x)] ----------------------------------
__global__ __launch_bounds__(256) void build_a(const float* __restrict__ x,
                                               unsigned short* __restrict__ Aop) {
  const long t = (long)blockIdx.x * 256 + threadIdx.x;
  const long e = t * 8;
  const long b = e >> 10;
  const int  d = (int)(e & 1023);
  const float4* xv = (const float4*)x;
  float4 v0 = xv[2 * t], v1 = xv[2 * t + 1];
  float vs[8] = {v0.x, v0.y, v0.z, v0.w, v1.x, v1.y, v1.z, v1.w};
  unsigned short sq[8] __attribute__((aligned(16)));
  unsigned short rw[8] __attribute__((aligned(16)));
#pragma unroll
  for (int j = 0; j < 8; ++j) {
    rw[j] = f2bf(vs[j]);
    sq[j] = f2bf(vs[j] * vs[j]);
  }
  *(uint4*)(Aop + b * K2 + d)        = *(uint4*)sq;
  *(uint4*)(Aop + b * K2 + D_SZ + d) = *(uint4*)rw;
}

// ---- fused: output copies of centers/sigma + W build + cn reduction ---------
__global__ __launch_bounds__(128) void prep_w(const float* __restrict__ centers,
                                              const float* __restrict__ sigma,
                                              float* __restrict__ out_centers,
                                              float* __restrict__ out_sigma,
                                              unsigned short* __restrict__ Wop,
                                              float* __restrict__ cn) {
  const int i = blockIdx.x;
  const int t = threadIdx.x;
  const long base = (long)i * D_SZ;
  const float4* cv = (const float4*)(centers + base);
  const float4* sv = (const float4*)(sigma + base);
  float4 c0 = cv[2 * t], c1 = cv[2 * t + 1];
  float4 s0 = sv[2 * t], s1 = sv[2 * t + 1];
  ((float4*)(out_centers + base))[2 * t]     = c0;
  ((float4*)(out_centers + base))[2 * t + 1] = c1;
  ((float4*)(out_sigma + base))[2 * t]       = s0;
  ((float4*)(out_sigma + base))[2 * t + 1]   = s1;
  float cs[8] = {c0.x, c0.y, c0.z, c0.w, c1.x, c1.y, c1.z, c1.w};
  float ss[8] = {s0.x, s0.y, s0.z, s0.w, s1.x, s1.y, s1.z, s1.w};
  unsigned short w1[8] __attribute__((aligned(16)));
  unsigned short w2[8] __attribute__((aligned(16)));
  float p = 0.0f;
#pragma unroll
  for (int j = 0; j < 8; ++j) {
    w1[j] = f2bf(-ss[j]);
    w2[j] = f2bf(2.0f * ss[j] * cs[j]);
    p += ss[j] * cs[j] * cs[j];
  }
  *(uint4*)(Wop + (long)i * K2 + t * 8)        = *(uint4*)w1;
  *(uint4*)(Wop + (long)i * K2 + D_SZ + t * 8) = *(uint4*)w2;
#pragma unroll
  for (int off = 32; off > 0; off >>= 1) p += __shfl_down(p, off, 64);
  __shared__ float red[2];
  if ((t & 63) == 0) red[t >> 6] = p;
  __syncthreads();
  if (t == 0) cn[i] = -(red[0] + red[1]);
}

// ---- GEMM -------------------------------------------------------------------
#define VM6()  asm volatile("s_waitcnt vmcnt(6)" ::: "memory")
#define VM2()  asm volatile("s_waitcnt vmcnt(2)" ::: "memory")
#define VM0()  asm volatile("s_waitcnt vmcnt(0)" ::: "memory")
#define NOW()  ((void)0)
#define SB()   __builtin_amdgcn_sched_barrier(0)
#define BAR()  __builtin_amdgcn_s_barrier()

// A tile KT -> ring buf C (4 loads: 64 rows each)
#define STAGE_A(C, KT)                                                          \
  do {                                                                          \
    __builtin_amdgcn_global_load_lds(                                           \
        (__attribute__((address_space(1))) void*)(aS + 0 * 64 * (long)K2 + (long)(KT) * 64), \
        (__attribute__((address_space(3))) void*)(&As[C][0 * 4096 + dstE]), 16, 0, 0);       \
    __builtin_amdgcn_global_load_lds(                                           \
        (__attribute__((address_space(1))) void*)(aS + 1 * 64 * (long)K2 + (long)(KT) * 64), \
        (__attribute__((address_space(3))) void*)(&As[C][1 * 4096 + dstE]), 16, 0, 0);       \
    __builtin_amdgcn_global_load_lds(                                           \
        (__attribute__((address_space(1))) void*)(aS + 2 * 64 * (long)K2 + (long)(KT) * 64), \
        (__attribute__((address_space(3))) void*)(&As[C][2 * 4096 + dstE]), 16, 0, 0);       \
    __builtin_amdgcn_global_load_lds(                                           \
        (__attribute__((address_space(1))) void*)(aS + 3 * 64 * (long)K2 + (long)(KT) * 64), \
        (__attribute__((address_space(3))) void*)(&As[C][3 * 4096 + dstE]), 16, 0, 0);       \
  } while (0)

// B half (tile KT, k-half KK) -> half-ring buf C (2 loads: 128 rows each)
#define STAGE_B(C, KT, KK)                                                      \
  do {                                                                          \
    __builtin_amdgcn_global_load_lds(                                           \
        (__attribute__((address_space(1))) void*)(bS + 0 * 128 * (long)K2 + (long)(KT) * 64 + (KK) * 32), \
        (__attribute__((address_space(3))) void*)(&Bs[C][0 * 4096 + dstE]), 16, 0, 0);                    \
    __builtin_amdgcn_global_load_lds(                                           \
        (__attribute__((address_space(1))) void*)(bS + 1 * 128 * (long)K2 + (long)(KT) * 64 + (KK) * 32), \
        (__attribute__((address_space(3))) void*)(&Bs[C][1 * 4096 + dstE]), 16, 0, 0);                    \
  } while (0)

// fragment reads (swizzled, conflict-free)
#define LDA(BUF, KX, MI) (*(const bf16x8*)(&As[BUF][(aAddr ^ ((KX) * 32)) + (MI) * 1024]))
#define LDB(BUF, NI)     (*(const bf16x8*)(&Bs[BUF][bAddr + (NI) * 512]))

#define MM32(A0, A1, A2, A3, A4, A5, A6, A7, B0, B1, B2, B3)                     \
  acc[0][0] = __builtin_amdgcn_mfma_f32_16x16x32_bf16(A0, B0, acc[0][0], 0,0,0); \
  acc[0][1] = __builtin_amdgcn_mfma_f32_16x16x32_bf16(A0, B1, acc[0][1], 0,0,0); \
  acc[0][2] = __builtin_amdgcn_mfma_f32_16x16x32_bf16(A0, B2, acc[0][2], 0,0,0); \
  acc[0][3] = __builtin_amdgcn_mfma_f32_16x16x32_bf16(A0, B3, acc[0][3], 0,0,0); \
  acc[1][0] = __builtin_amdgcn_mfma_f32_16x16x32_bf16(A1, B0, acc[1][0], 0,0,0); \
  acc[1][1] = __builtin_amdgcn_mfma_f32_16x16x32_bf16(A1, B1, acc[1][1], 0,0,0); \
  acc[1][2] = __builtin_amdgcn_mfma_f32_16x16x32_bf16(A1, B2, acc[1][2], 0,0,0); \
  acc[1][3] = __builtin_amdgcn_mfma_f32_16x16x32_bf16(A1, B3, acc[1][3], 0,0,0); \
  acc[2][0] = __builtin_amdgcn_mfma_f32_16x16x32_bf16(A2, B0, acc[2][0], 0,0,0); \
  acc[2][1] = __builtin_amdgcn_mfma_f32_16x16x32_bf16(A2, B1, acc[2][1], 0,0,0); \
  acc[2][2] = __builtin_amdgcn_mfma_f32_16x16x32_bf16(A2, B2, acc[2][2], 0,0,0); \
  acc[2][3] = __builtin_amdgcn_mfma_f32_16x16x32_bf16(A2, B3, acc[2][3], 0,0,0); \
  acc[3][0] = __builtin_amdgcn_mfma_f32_16x16x32_bf16(A3, B0, acc[3][0], 0,0,0); \
  acc[3][1] = __builtin_amdgcn_mfma_f32_16x16x32_bf16(A3, B1, acc[3][1], 0,0,0); \
  acc[3][2] = __builtin_amdgcn_mfma_f32_16x16x32_bf16(A3, B2, acc[3][2], 0,0,0); \
  acc[3][3] = __builtin_amdgcn_mfma_f32_16x16x32_bf16(A3, B3, acc[3][3], 0,0,0); \
  acc[4][0] = __builtin_amdgcn_mfma_f32_16x16x32_bf16(A4, B0, acc[4][0], 0,0,0); \
  acc[4][1] = __builtin_amdgcn_mfma_f32_16x16x32_bf16(A4, B1, acc[4][1], 0,0,0); \
  acc[4][2] = __builtin_amdgcn_mfma_f32_16x16x32_bf16(A4, B2, acc[4][2], 0,0,0); \
  acc[4][3] = __builtin_amdgcn_mfma_f32_16x16x32_bf16(A4, B3, acc[4][3], 0,0,0); \
  acc[5][0] = __builtin_amdgcn_mfma_f32_16x16x32_bf16(A5, B0, acc[5][0], 0,0,0); \
  acc[5][1] = __builtin_amdgcn_mfma_f32_16x16x32_bf16(A5, B1, acc[5][1], 0,0,0); \
  acc[5][2] = __builtin_amdgcn_mfma_f32_16x16x32_bf16(A5, B2, acc[5][2], 0,0,0); \
  acc[5][3] = __builtin_amdgcn_mfma_f32_16x16x32_bf16(A5, B3, acc[5][3], 0,0,0); \
  acc[6][0] = __builtin_amdgcn_mfma_f32_16x16x32_bf16(A6, B0, acc[6][0], 0,0,0); \
  acc[6][1] = __builtin_amdgcn_mfma_f32_16x16x32_bf16(A6, B1, acc[6][1], 0,0,0); \
  acc[6][2] = __builtin_amdgcn_mfma_f32_16x16x32_bf16(A6, B2, acc[6][2], 0,0,0); \
  acc[6][3] = __builtin_amdgcn_mfma_f32_16x16x32_bf16(A6, B3, acc[6][3], 0,0,0); \
  acc[7][0] = __builtin_amdgcn_mfma_f32_16x16x32_bf16(A7, B0, acc[7][0], 0,0,0); \
  acc[7][1] = __builtin_amdgcn_mfma_f32_16x16x32_bf16(A7, B1, acc[7][1], 0,0,0); \
  acc[7][2] = __builtin_amdgcn_mfma_f32_16x16x32_bf16(A7, B2, acc[7][2], 0,0,0); \
  acc[7][3] = __builtin_amdgcn_mfma_f32_16x16x32_bf16(A7, B3, acc[7][3], 0,0,0);

// One K-tile U. kk0: stage B(U+1,h1)->BS0 + A(U+2)->AST; prefetch aQ (kk1) +
// bQ (next half); SB; setprio MFMA(aP,bP) setprio; vmcnt; BAR.
// kk1: stage B(U+2,h0)->BS1; prefetch aP (tile U+1 kk0) + bP; SB;
// setprio MFMA(aQ,bQ) setprio; vmcnt; BAR.
#define TILE(AC, AN, AST, P1, P2, BS0, BS1, U, STGA, SB0_, SB1_, W0, W1, PRE)  \
  { /* kk0 */                                                                  \
    if (SB0_) STAGE_B(BS0, (U) + 1, 1);                                        \
    if (STGA) STAGE_A(AST, (U) + 2);                                           \
    aQ0 = LDA(AC, 1, 0); aQ1 = LDA(AC, 1, 1);                                  \
    aQ2 = LDA(AC, 1, 2); aQ3 = LDA(AC, 1, 3);                                  \
    aQ4 = LDA(AC, 1, 4); aQ5 = LDA(AC, 1, 5);                                  \
    aQ6 = LDA(AC, 1, 6); aQ7 = LDA(AC, 1, 7);                                  \
    bQ0 = LDB(P1, 0); bQ1 = LDB(P1, 1); bQ2 = LDB(P1, 2); bQ3 = LDB(P1, 3);    \
    SB();                                                                      \
    __builtin_amdgcn_s_setprio(1);                                             \
    MM32(aP0, aP1, aP2, aP3, aP4, aP5, aP6, aP7, bP0, bP1, bP2, bP3)           \
    __builtin_amdgcn_s_setprio(0);                                             \
    SB(); W0(); SB(); BAR();                                                   \
  }                                                                            \
  { /* kk1 */                                                                  \
    if (SB1_) STAGE_B(BS1, (U) + 2, 0);                                        \
    if (PRE) {                                                                 \
      aP0 = LDA(AN, 0, 0); aP1 = LDA(AN, 0, 1);                                \
      aP2 = LDA(AN, 0, 2); aP3 = LDA(AN, 0, 3);                                \
      aP4 = LDA(AN, 0, 4); aP5 = LDA(AN, 0, 5);                                \
      aP6 = LDA(AN, 0, 6); aP7 = LDA(AN, 0, 7);                                \
      bP0 = LDB(P2, 0); bP1 = LDB(P2, 1); bP2 = LDB(P2, 2); bP3 = LDB(P2, 3);  \
    }                                                                          \
    SB();                                                                      \
    __builtin_amdgcn_s_setprio(1);                                             \
    MM32(aQ0, aQ1, aQ2, aQ3, aQ4, aQ5, aQ6, aQ7, bQ0, bQ1, bQ2, bQ3)          \
    __builtin_amdgcn_s_setprio(0);                                             \
    SB(); W1(); SB(); BAR();                                                   \
  }

__global__ __launch_bounds__(512, 2) void gemm256(const unsigned short* __restrict__ A,
                                                  const unsigned short* __restrict__ W,
                                                  const float* __restrict__ cn,
                                                  float* __restrict__ out) {
  // A: ring-3 [3][256 rows][64 k], phys 16B-slot = logical ^ (row&7)      (96KB)
  // B: half-ring-3 [3][256 rows][32 k], phys slot = (logical + (row>>1))&3 (48KB)
  __shared__ __attribute__((aligned(16))) unsigned short As[3][16384];
  __shared__ __attribute__((aligned(16))) unsigned short Bs[3][8192];

  const int tid  = threadIdx.x;
  const int lane = tid & 63;
  const int wave = tid >> 6;
  const int wr = wave >> 2;              // 0..1 -> 128-row half of M
  const int wc = wave & 3;               // 0..3 -> 64-row slice of N

  // XCD-aware block swizzle: xcd owns 4 m-panels x 8 n-tiles
  const int bid = blockIdx.x;
  const int xcd = bid & 7, idx = bid >> 3;
  const long rowBase = (long)(xcd * 4 + (idx >> 3)) * 256;
  const long colBase = (long)(idx & 7) * 256;

  // A staging: rows (tid>>3)+{0,64,128,192}; phys slot tid&7 <- logical (tid&7)^(row&7)
  const int sr = tid >> 3;
  const int sl = (tid & 7) ^ (sr & 7);
  const unsigned short* aS = A + (rowBase + sr) * (long)K2 + sl * 8;
  // B staging: rows (tid>>2)+{0,128}; phys slot tid&3 <- logical ((tid&3)-(row>>1))&3
  const int br = tid >> 2;
  const int bl = ((tid & 3) - (tid >> 3)) & 3;
  const unsigned short* bS = W + (colBase + br) * (long)K2 + bl * 8;
  const int dstE = tid * 8;

  // fragment read bases
  const int l15 = lane & 15, l7 = lane & 7, q = lane >> 4;
  const int aAddr = (wr * 128 + l15) * 64 + ((q ^ l7) * 8);        // kk0; kk1 = ^32
  const int bAddr = (wc * 64 + l15) * 32 + (((q + (l15 >> 1)) & 3) * 8);

  f32x4 acc[8][4];
#pragma unroll
  for (int i = 0; i < 8; ++i)
#pragma unroll
    for (int j = 0; j < 4; ++j) acc[i][j] = (f32x4){0.f, 0.f, 0.f, 0.f};

  bf16x8 aP0, aP1, aP2, aP3, aP4, aP5, aP6, aP7;
  bf16x8 aQ0, aQ1, aQ2, aQ3, aQ4, aQ5, aQ6, aQ7;
  bf16x8 bP0, bP1, bP2, bP3, bQ0, bQ1, bQ2, bQ3;

  // prologue: A(0)->0, Bh0->0, Bh1->1, A(1)->1, Bh2->2  (14 loads)
  STAGE_A(0, 0);
  STAGE_B(0, 0, 0);
  STAGE_B(1, 0, 1);
  STAGE_A(1, 1);
  STAGE_B(2, 1, 0);
  VM6(); SB(); BAR();   // A0,Bh0,Bh1 landed; A1,Bh2 in flight
  // preload phase-0 fragments
  aP0 = LDA(0, 0, 0); aP1 = LDA(0, 0, 1); aP2 = LDA(0, 0, 2); aP3 = LDA(0, 0, 3);
  aP4 = LDA(0, 0, 4); aP5 = LDA(0, 0, 5); aP6 = LDA(0, 0, 6); aP7 = LDA(0, 0, 7);
  bP0 = LDB(0, 0); bP1 = LDB(0, 1); bP2 = LDB(0, 2); bP3 = LDB(0, 3);

  // tiles 0..29: period 3  (B buf for half h = h%3; A buf for tile t = t%3)
#pragma unroll 1
  for (int u = 0; u < 30; u += 3) {
    TILE(0, 1, 2, 1, 2, 0, 1, u + 0, 1, 1, 1, VM6, VM6, 1);
    TILE(1, 2, 0, 0, 1, 2, 0, u + 1, 1, 1, 1, VM6, VM6, 1);
    TILE(2, 0, 1, 2, 0, 1, 2, u + 2, 1, 1, 1, VM6, VM6, 1);
  }
  // tail: tile 30 (stage only B(31,k1)), tile 31 (no stages, no final prefetch)
  TILE(0, 1, 2, 1, 2, 0, 1, 30, 0, 1, 0, VM2, VM0, 1);
  TILE(1, 2, 0, 0, 1, 2, 0, 31, 0, 0, 0, NOW, NOW, 0);

  // epilogue: C/D layout col=lane&15, row=(lane>>4)*4+j (m89-verified)
  const int crow = (lane >> 4) * 4;
  const int ccol = lane & 15;
#pragma unroll
  for (int ni = 0; ni < 4; ++ni) {
    const long col = colBase + wc * 64 + ni * 16 + ccol;
    const float c = cn[col];
#pragma unroll
    for (int mi = 0; mi < 8; ++mi) {
      const long row = rowBase + wr * 128 + mi * 16 + crow;
      float* o = out + row * C_SZ + col;
#pragma unroll
      for (int j = 0; j < 4; ++j) o[(long)j * C_SZ] = acc[mi][ni][j] + c;
    }
  }
}

extern "C" void kernel_launch(void* const* d_in, const int* in_sizes, int n_in,
                              void* d_out, int out_size, void* d_ws, size_t ws_size,
                              hipStream_t stream) {
  const float* x       = (const float*)d_in[0];
  const float* centers = (const float*)d_in[1];
  const float* sigma   = (const float*)d_in[2];
  float* out = (float*)d_out;

  unsigned short* Aop = (unsigned short*)d_ws;            // 8192*2048 bf16
  unsigned short* Wop = Aop + (long)B_SZ * K2;            // 2048*2048 bf16
  float* cnp = (float*)(Wop + (long)C_SZ * K2);           // 2048 f32

  build_a<<<B_SZ * D_SZ / 8 / 256, 256, 0, stream>>>(x, Aop);
  prep_w<<<C_SZ, 128, 0, stream>>>(centers, sigma,
                                   out, out + (size_t)C_SZ * D_SZ, Wop, cnp);

  float* out2 = out + (size_t)2 * C_SZ * D_SZ;
  gemm256<<<256, 512, 0, stream>>>(Aop, Wop, cnp, out2);
}

// Round 8
// 90.772 us; speedup vs baseline: 1.1267x; 1.0650x over previous
//
#include <hip/hip_runtime.h>
#include <hip/hip_bf16.h>

// dce_loss: out = concat(centers, sigma, -dist)
// -dist[b,i] = sum_k A[b,k]*W[i,k] + cn[i],  A=[bf16(x^2)|bf16(x)], W=[-sigma|2*sigma*c]
// GEMM 256x256, BK=64, 8 waves, 16x16x32 MFMA, m201-style 4-phase/K-tile:
// per phase {ds_reads(4 or 8) ; 2x global_load_lds} BAR lgkm0 SB setprio(1)
// 16xMFMA setprio(0) [vmcnt(6) at ph b/d] BAR.
// A: ring-3 full tiles (96KB), slot^=(row&7). B: ring-3 k-halves (48KB),
// slot=(q+(row>>1))&3. Ledger: periodic in-flight=6, waits counted, never 0
// until tail. Tail: vmcnt 2/2 then 0.

#define B_SZ 8192
#define C_SZ 2048
#define D_SZ 1024
#define K2   2048

typedef __attribute__((ext_vector_type(4))) float f32x4;
typedef __attribute__((ext_vector_type(8))) short bf16x8;

static __device__ __forceinline__ unsigned short f2bf(float f) {
  union { float f; unsigned int u; } v; v.f = f;
  unsigned int r = v.u + 0x7fffu + ((v.u >> 16) & 1u);   // RNE, finite inputs
  return (unsigned short)(r >> 16);
}

// ---- preprocess: A = [bf16(x^2) | bf16(x)] ----------------------------------
__global__ __launch_bounds__(256) void build_a(const float* __restrict__ x,
                                               unsigned short* __restrict__ Aop) {
  const long t = (long)blockIdx.x * 256 + threadIdx.x;
  const long e = t * 8;
  const long b = e >> 10;
  const int  d = (int)(e & 1023);
  const float4* xv = (const float4*)x;
  float4 v0 = xv[2 * t], v1 = xv[2 * t + 1];
  float vs[8] = {v0.x, v0.y, v0.z, v0.w, v1.x, v1.y, v1.z, v1.w};
  unsigned short sq[8] __attribute__((aligned(16)));
  unsigned short rw[8] __attribute__((aligned(16)));
#pragma unroll
  for (int j = 0; j < 8; ++j) {
    rw[j] = f2bf(vs[j]);
    sq[j] = f2bf(vs[j] * vs[j]);
  }
  *(uint4*)(Aop + b * K2 + d)        = *(uint4*)sq;
  *(uint4*)(Aop + b * K2 + D_SZ + d) = *(uint4*)rw;
}

// ---- fused: output copies of centers/sigma + W build + cn reduction ---------
__global__ __launch_bounds__(128) void prep_w(const float* __restrict__ centers,
                                              const float* __restrict__ sigma,
                                              float* __restrict__ out_centers,
                                              float* __restrict__ out_sigma,
                                              unsigned short* __restrict__ Wop,
                                              float* __restrict__ cn) {
  const int i = blockIdx.x;
  const int t = threadIdx.x;
  const long base = (long)i * D_SZ;
  const float4* cv = (const float4*)(centers + base);
  const float4* sv = (const float4*)(sigma + base);
  float4 c0 = cv[2 * t], c1 = cv[2 * t + 1];
  float4 s0 = sv[2 * t], s1 = sv[2 * t + 1];
  ((float4*)(out_centers + base))[2 * t]     = c0;
  ((float4*)(out_centers + base))[2 * t + 1] = c1;
  ((float4*)(out_sigma + base))[2 * t]       = s0;
  ((float4*)(out_sigma + base))[2 * t + 1]   = s1;
  float cs[8] = {c0.x, c0.y, c0.z, c0.w, c1.x, c1.y, c1.z, c1.w};
  float ss[8] = {s0.x, s0.y, s0.z, s0.w, s1.x, s1.y, s1.z, s1.w};
  unsigned short w1[8] __attribute__((aligned(16)));
  unsigned short w2[8] __attribute__((aligned(16)));
  float p = 0.0f;
#pragma unroll
  for (int j = 0; j < 8; ++j) {
    w1[j] = f2bf(-ss[j]);
    w2[j] = f2bf(2.0f * ss[j] * cs[j]);
    p += ss[j] * cs[j] * cs[j];
  }
  *(uint4*)(Wop + (long)i * K2 + t * 8)        = *(uint4*)w1;
  *(uint4*)(Wop + (long)i * K2 + D_SZ + t * 8) = *(uint4*)w2;
#pragma unroll
  for (int off = 32; off > 0; off >>= 1) p += __shfl_down(p, off, 64);
  __shared__ float red[2];
  if ((t & 63) == 0) red[t >> 6] = p;
  __syncthreads();
  if (t == 0) cn[i] = -(red[0] + red[1]);
}

// ---- GEMM -------------------------------------------------------------------
#define VM6()  asm volatile("s_waitcnt vmcnt(6)" ::: "memory")
#define VM2()  asm volatile("s_waitcnt vmcnt(2)" ::: "memory")
#define VM0()  asm volatile("s_waitcnt vmcnt(0)" ::: "memory")
#define NOW()  ((void)0)
#define LGKM0() asm volatile("s_waitcnt lgkmcnt(0)" ::: "memory")
#define SB()   __builtin_amdgcn_sched_barrier(0)
#define BAR()  __builtin_amdgcn_s_barrier()

// stage 64 rows (one global_load_lds pair-half) of A tile KT, row block H*128+J*64
#define STAGE_A2(C, KT, H)                                                      \
  do {                                                                          \
    __builtin_amdgcn_global_load_lds(                                           \
        (__attribute__((address_space(1))) void*)(aS + ((H)*128 + 0) * (long)K2 + (long)(KT)*64),  \
        (__attribute__((address_space(3))) void*)(&As[C][(H)*8192 + dstE]), 16, 0, 0);             \
    __builtin_amdgcn_global_load_lds(                                           \
        (__attribute__((address_space(1))) void*)(aS + ((H)*128 + 64) * (long)K2 + (long)(KT)*64), \
        (__attribute__((address_space(3))) void*)(&As[C][(H)*8192 + 4096 + dstE]), 16, 0, 0);      \
  } while (0)

// B k-half (tile KT, half KK) -> ring slot C (2 loads: 128 rows each)
#define STAGE_B(C, KT, KK)                                                      \
  do {                                                                          \
    __builtin_amdgcn_global_load_lds(                                           \
        (__attribute__((address_space(1))) void*)(bS + 0 * 128 * (long)K2 + (long)(KT)*64 + (KK)*32), \
        (__attribute__((address_space(3))) void*)(&Bs[C][0 * 4096 + dstE]), 16, 0, 0);                \
    __builtin_amdgcn_global_load_lds(                                           \
        (__attribute__((address_space(1))) void*)(bS + 1 * 128 * (long)K2 + (long)(KT)*64 + (KK)*32), \
        (__attribute__((address_space(3))) void*)(&Bs[C][1 * 4096 + dstE]), 16, 0, 0);                \
  } while (0)

// fragment reads (swizzled, conflict-free; both patterns measured 0-conflict)
#define LDA(BUF, KX, MI) (*(const bf16x8*)(&As[BUF][(aAddr ^ ((KX) * 32)) + (MI) * 1024]))
#define LDB(BUF, NI)     (*(const bf16x8*)(&Bs[BUF][bAddr + (NI) * 512]))

#define MFMA16 __builtin_amdgcn_mfma_f32_16x16x32_bf16

// 16 MFMA: 4 mi x 4 ni into acc[R..R+3][0..3]
#define MM16(A0, A1, A2, A3, B0, B1, B2, B3, R)        \
  acc[(R)+0][0] = MFMA16(A0, B0, acc[(R)+0][0], 0,0,0);\
  acc[(R)+0][1] = MFMA16(A0, B1, acc[(R)+0][1], 0,0,0);\
  acc[(R)+0][2] = MFMA16(A0, B2, acc[(R)+0][2], 0,0,0);\
  acc[(R)+0][3] = MFMA16(A0, B3, acc[(R)+0][3], 0,0,0);\
  acc[(R)+1][0] = MFMA16(A1, B0, acc[(R)+1][0], 0,0,0);\
  acc[(R)+1][1] = MFMA16(A1, B1, acc[(R)+1][1], 0,0,0);\
  acc[(R)+1][2] = MFMA16(A1, B2, acc[(R)+1][2], 0,0,0);\
  acc[(R)+1][3] = MFMA16(A1, B3, acc[(R)+1][3], 0,0,0);\
  acc[(R)+2][0] = MFMA16(A2, B0, acc[(R)+2][0], 0,0,0);\
  acc[(R)+2][1] = MFMA16(A2, B1, acc[(R)+2][1], 0,0,0);\
  acc[(R)+2][2] = MFMA16(A2, B2, acc[(R)+2][2], 0,0,0);\
  acc[(R)+2][3] = MFMA16(A2, B3, acc[(R)+2][3], 0,0,0);\
  acc[(R)+3][0] = MFMA16(A3, B0, acc[(R)+3][0], 0,0,0);\
  acc[(R)+3][1] = MFMA16(A3, B1, acc[(R)+3][1], 0,0,0);\
  acc[(R)+3][2] = MFMA16(A3, B2, acc[(R)+3][2], 0,0,0);\
  acc[(R)+3][3] = MFMA16(A3, B3, acc[(R)+3][3], 0,0,0);

#define PH_MID() BAR(); LGKM0(); SB(); __builtin_amdgcn_s_setprio(1)
#define PH_END(WW) __builtin_amdgcn_s_setprio(0); SB(); WW(); SB(); BAR()

// One K-tile U: 4 phases of 16 MFMA. AC = A ring slot (u%3), AST = (u+2)%3.
// BH0/BH1 = B slots for (u,h0)/(u,h1). Stages: ph a/b: A(U+2) halves -> AST;
// ph c: B(U+1,h1) -> BH0 (safe: BH0 reads done at ph b barrier);
// ph d: B(U+2,h0) -> BH1 (safe: BH1 reads done at ph c barrier).
#define TILE8(AC, AST, BH0, BH1, U, STGA, STGB1, STGB2, WB, WD)                \
  { /* ph a: A(k0, mi0-3) x B(k0) */                                           \
    aA0 = LDA(AC, 0, 0); aA1 = LDA(AC, 0, 1);                                  \
    aA2 = LDA(AC, 0, 2); aA3 = LDA(AC, 0, 3);                                  \
    bP0 = LDB(BH0, 0); bP1 = LDB(BH0, 1);                                      \
    bP2 = LDB(BH0, 2); bP3 = LDB(BH0, 3);                                      \
    if (STGA) STAGE_A2(AST, (U) + 2, 0);                                       \
    PH_MID();                                                                  \
    MM16(aA0, aA1, aA2, aA3, bP0, bP1, bP2, bP3, 0)                            \
    PH_END(NOW);                                                               \
  }                                                                            \
  { /* ph b: A(k0, mi4-7) x B(k0) */                                           \
    aB0 = LDA(AC, 0, 4); aB1 = LDA(AC, 0, 5);                                  \
    aB2 = LDA(AC, 0, 6); aB3 = LDA(AC, 0, 7);                                  \
    if (STGA) STAGE_A2(AST, (U) + 2, 1);                                       \
    PH_MID();                                                                  \
    MM16(aB0, aB1, aB2, aB3, bP0, bP1, bP2, bP3, 4)                            \
    PH_END(WB);                                                                \
  }                                                                            \
  { /* ph c: A(k1, mi0-3) x B(k1) */                                           \
    aA0 = LDA(AC, 1, 0); aA1 = LDA(AC, 1, 1);                                  \
    aA2 = LDA(AC, 1, 2); aA3 = LDA(AC, 1, 3);                                  \
    bQ0 = LDB(BH1, 0); bQ1 = LDB(BH1, 1);                                      \
    bQ2 = LDB(BH1, 2); bQ3 = LDB(BH1, 3);                                      \
    if (STGB1) STAGE_B(BH0, (U) + 1, 1);                                       \
    PH_MID();                                                                  \
    MM16(aA0, aA1, aA2, aA3, bQ0, bQ1, bQ2, bQ3, 0)                            \
    PH_END(NOW);                                                               \
  }                                                                            \
  { /* ph d: A(k1, mi4-7) x B(k1) */                                           \
    aB0 = LDA(AC, 1, 4); aB1 = LDA(AC, 1, 5);                                  \
    aB2 = LDA(AC, 1, 6); aB3 = LDA(AC, 1, 7);                                  \
    if (STGB2) STAGE_B(BH1, (U) + 2, 0);                                       \
    PH_MID();                                                                  \
    MM16(aB0, aB1, aB2, aB3, bQ0, bQ1, bQ2, bQ3, 4)                            \
    PH_END(WD);                                                                \
  }

__global__ __launch_bounds__(512, 2) void gemm256(const unsigned short* __restrict__ A,
                                                  const unsigned short* __restrict__ W,
                                                  const float* __restrict__ cn,
                                                  float* __restrict__ out) {
  // A: ring-3 [3][256 rows][64 k], phys 16B-slot = logical ^ (row&7)       (96KB)
  // B: half ring-3 [3][256 rows][32 k], phys slot = (logical + (row>>1))&3 (48KB)
  __shared__ __attribute__((aligned(16))) unsigned short As[3][16384];
  __shared__ __attribute__((aligned(16))) unsigned short Bs[3][8192];

  const int tid  = threadIdx.x;
  const int lane = tid & 63;
  const int wave = tid >> 6;
  const int wr = wave >> 2;              // 0..1 -> 128-row half of M
  const int wc = wave & 3;               // 0..3 -> 64-row slice of N

  // XCD-aware block swizzle: xcd owns 4 m-panels x 8 n-tiles (A panel = 4MB L2)
  const int bid = blockIdx.x;
  const int xcd = bid & 7, idx = bid >> 3;
  const long rowBase = (long)(xcd * 4 + (idx >> 3)) * 256;
  const long colBase = (long)(idx & 7) * 256;

  // A staging: row (tid>>3)+{0,64,...}; phys slot tid&7 <- logical (tid&7)^(row&7)
  const int sr = tid >> 3;
  const int sl = (tid & 7) ^ (sr & 7);
  const unsigned short* aS = A + (rowBase + sr) * (long)K2 + sl * 8;
  // B staging: rows (tid>>2)+{0,128}; phys slot tid&3 <- logical ((tid&3)-(row>>1))&3
  const int br = tid >> 2;
  const int bl = ((tid & 3) - (tid >> 3)) & 3;
  const unsigned short* bS = W + (colBase + br) * (long)K2 + bl * 8;
  const int dstE = tid * 8;

  // fragment read bases (conflict-free swizzles)
  const int l15 = lane & 15, l7 = lane & 7, q = lane >> 4;
  const int aAddr = (wr * 128 + l15) * 64 + ((q ^ l7) * 8);        // k0; k1 = ^32
  const int bAddr = (wc * 64 + l15) * 32 + (((q + (l15 >> 1)) & 3) * 8);

  f32x4 acc[8][4];
#pragma unroll
  for (int i = 0; i < 8; ++i)
#pragma unroll
    for (int j = 0; j < 4; ++j) acc[i][j] = (f32x4){0.f, 0.f, 0.f, 0.f};

  bf16x8 aA0, aA1, aA2, aA3, aB0, aB1, aB2, aB3;
  bf16x8 bP0, bP1, bP2, bP3, bQ0, bQ1, bQ2, bQ3;

  // prologue (order defines the vmcnt ledger):
  // [A(0)x4, B(0,h0)x2, A(1)x4, B(0,h1)x2, B(1,h0)x2] = 14 loads; drain to 6.
  STAGE_A2(0, 0, 0); STAGE_A2(0, 0, 1);   // A(0) -> slot 0
  STAGE_B(0, 0, 0);                        // B(0,h0) -> slot 0
  STAGE_A2(1, 1, 0); STAGE_A2(1, 1, 1);   // A(1) -> slot 1
  STAGE_B(1, 0, 1);                        // B(0,h1) -> slot 1
  STAGE_B(2, 1, 0);                        // B(1,h0) -> slot 2
  VM6(); SB(); BAR();
  // in-flight: [A(1)l3,l4, B(0,h1)x2, B(1,h0)x2] — the periodic invariant.

  // tiles 0..29 (period 3): AC=u%3, AST=(u+2)%3, BH0=(2u)%3, BH1=(2u+1)%3
#pragma unroll 1
  for (int u = 0; u < 30; u += 3) {
    TILE8(0, 2, 0, 1, u + 0, 1, 1, 1, VM6, VM6);
    TILE8(1, 0, 2, 0, u + 1, 1, 1, 1, VM6, VM6);
    TILE8(2, 1, 1, 2, u + 2, 1, 1, 1, VM6, VM6);
  }
  // tile 30: no A stage; stage B(31,h1); waits drain 2 then 2
  TILE8(0, 2, 0, 1, 30, 0, 1, 0, VM2, VM2);
  // tile 31: no stages; drain rest before ph c's B(31,h1) read
  TILE8(1, 0, 2, 0, 31, 0, 0, 0, VM0, NOW);

  // epilogue: C/D layout col=lane&15, row=(lane>>4)*4+j (m89-verified)
  const int crow = (lane >> 4) * 4;
  const int ccol = lane & 15;
#pragma unroll
  for (int ni = 0; ni < 4; ++ni) {
    const long col = colBase + wc * 64 + ni * 16 + ccol;
    const float c = cn[col];
#pragma unroll
    for (int mi = 0; mi < 8; ++mi) {
      const long row = rowBase + wr * 128 + mi * 16 + crow;
      float* o = out + row * C_SZ + col;
#pragma unroll
      for (int j = 0; j < 4; ++j) o[(long)j * C_SZ] = acc[mi][ni][j] + c;
    }
  }
}

extern "C" void kernel_launch(void* const* d_in, const int* in_sizes, int n_in,
                              void* d_out, int out_size, void* d_ws, size_t ws_size,
                              hipStream_t stream) {
  const float* x       = (const float*)d_in[0];
  const float* centers = (const float*)d_in[1];
  const float* sigma   = (const float*)d_in[2];
  float* out = (float*)d_out;

  unsigned short* Aop = (unsigned short*)d_ws;            // 8192*2048 bf16
  unsigned short* Wop = Aop + (long)B_SZ * K2;            // 2048*2048 bf16
  float* cnp = (float*)(Wop + (long)C_SZ * K2);           // 2048 f32

  build_a<<<B_SZ * D_SZ / 8 / 256, 256, 0, stream>>>(x, Aop);
  prep_w<<<C_SZ, 128, 0, stream>>>(centers, sigma,
                                   out, out + (size_t)C_SZ * D_SZ, Wop, cnp);

  float* out2 = out + (size_t)2 * C_SZ * D_SZ;
  gemm256<<<256, 512, 0, stream>>>(Aop, Wop, cnp, out2);
}

// Round 9
// 84.978 us; speedup vs baseline: 1.2035x; 1.0682x over previous
//
#include <hip/hip_runtime.h>
#include <hip/hip_bf16.h>

// dce_loss: out = concat(centers, sigma, -dist)
// -dist[b,i] = sum_k A[b,k]*W[i,k] + cn[i],  A=[bf16(x^2)|bf16(x)], W=[-sigma|2*sigma*c]
// GEMM 256x256, BK=64, 8 waves. A: ring-3 LDS (96KB), stage dist 2 tiles,
// slot^=(row&7). B: ring-3 half-tile LDS (48KB), slot=(q+(row>>1))&3 (0-conflict,
// verified r7/r8). All fragments (8A+4B) prefetched one phase ahead into regs;
// compiler-scheduled interleave (no SB/setprio — r7 showed they hurt);
// vmcnt(6) at each phase end (counted, never 0 until tail). 2 barriers/tile.

#define B_SZ 8192
#define C_SZ 2048
#define D_SZ 1024
#define K2   2048

typedef __attribute__((ext_vector_type(4))) float f32x4;
typedef __attribute__((ext_vector_type(8))) short bf16x8;

static __device__ __forceinline__ unsigned short f2bf(float f) {
  union { float f; unsigned int u; } v; v.f = f;
  unsigned int r = v.u + 0x7fffu + ((v.u >> 16) & 1u);   // RNE, finite inputs
  return (unsigned short)(r >> 16);
}

// ---- preprocess: A = [bf16(x^2) | bf16(x)] ----------------------------------
__global__ __launch_bounds__(256) void build_a(const float* __restrict__ x,
                                               unsigned short* __restrict__ Aop) {
  const long t = (long)blockIdx.x * 256 + threadIdx.x;
  const long e = t * 8;
  const long b = e >> 10;
  const int  d = (int)(e & 1023);
  const float4* xv = (const float4*)x;
  float4 v0 = xv[2 * t], v1 = xv[2 * t + 1];
  float vs[8] = {v0.x, v0.y, v0.z, v0.w, v1.x, v1.y, v1.z, v1.w};
  unsigned short sq[8] __attribute__((aligned(16)));
  unsigned short rw[8] __attribute__((aligned(16)));
#pragma unroll
  for (int j = 0; j < 8; ++j) {
    rw[j] = f2bf(vs[j]);
    sq[j] = f2bf(vs[j] * vs[j]);
  }
  *(uint4*)(Aop + b * K2 + d)        = *(uint4*)sq;
  *(uint4*)(Aop + b * K2 + D_SZ + d) = *(uint4*)rw;
}

// ---- fused: output copies of centers/sigma + W build + cn reduction ---------
__global__ __launch_bounds__(128) void prep_w(const float* __restrict__ centers,
                                              const float* __restrict__ sigma,
                                              float* __restrict__ out_centers,
                                              float* __restrict__ out_sigma,
                                              unsigned short* __restrict__ Wop,
                                              float* __restrict__ cn) {
  const int i = blockIdx.x;
  const int t = threadIdx.x;
  const long base = (long)i * D_SZ;
  const float4* cv = (const float4*)(centers + base);
  const float4* sv = (const float4*)(sigma + base);
  float4 c0 = cv[2 * t], c1 = cv[2 * t + 1];
  float4 s0 = sv[2 * t], s1 = sv[2 * t + 1];
  ((float4*)(out_centers + base))[2 * t]     = c0;
  ((float4*)(out_centers + base))[2 * t + 1] = c1;
  ((float4*)(out_sigma + base))[2 * t]       = s0;
  ((float4*)(out_sigma + base))[2 * t + 1]   = s1;
  float cs[8] = {c0.x, c0.y, c0.z, c0.w, c1.x, c1.y, c1.z, c1.w};
  float ss[8] = {s0.x, s0.y, s0.z, s0.w, s1.x, s1.y, s1.z, s1.w};
  unsigned short w1[8] __attribute__((aligned(16)));
  unsigned short w2[8] __attribute__((aligned(16)));
  float p = 0.0f;
#pragma unroll
  for (int j = 0; j < 8; ++j) {
    w1[j] = f2bf(-ss[j]);
    w2[j] = f2bf(2.0f * ss[j] * cs[j]);
    p += ss[j] * cs[j] * cs[j];
  }
  *(uint4*)(Wop + (long)i * K2 + t * 8)        = *(uint4*)w1;
  *(uint4*)(Wop + (long)i * K2 + D_SZ + t * 8) = *(uint4*)w2;
#pragma unroll
  for (int off = 32; off > 0; off >>= 1) p += __shfl_down(p, off, 64);
  __shared__ float red[2];
  if ((t & 63) == 0) red[t >> 6] = p;
  __syncthreads();
  if (t == 0) cn[i] = -(red[0] + red[1]);
}

// ---- GEMM -------------------------------------------------------------------
#define VM6()  asm volatile("s_waitcnt vmcnt(6)" ::: "memory")
#define VM2()  asm volatile("s_waitcnt vmcnt(2)" ::: "memory")
#define VM0()  asm volatile("s_waitcnt vmcnt(0)" ::: "memory")
#define NOW()  ((void)0)
#define SB()   __builtin_amdgcn_sched_barrier(0)
#define BAR()  __builtin_amdgcn_s_barrier()

// A tile KT -> ring buf C (4 loads: 64 rows each)
#define STAGE_A(C, KT)                                                          \
  do {                                                                          \
    __builtin_amdgcn_global_load_lds(                                           \
        (__attribute__((address_space(1))) void*)(aS + 0 * 64 * (long)K2 + (long)(KT) * 64), \
        (__attribute__((address_space(3))) void*)(&As[C][0 * 4096 + dstE]), 16, 0, 0);       \
    __builtin_amdgcn_global_load_lds(                                           \
        (__attribute__((address_space(1))) void*)(aS + 1 * 64 * (long)K2 + (long)(KT) * 64), \
        (__attribute__((address_space(3))) void*)(&As[C][1 * 4096 + dstE]), 16, 0, 0);       \
    __builtin_amdgcn_global_load_lds(                                           \
        (__attribute__((address_space(1))) void*)(aS + 2 * 64 * (long)K2 + (long)(KT) * 64), \
        (__attribute__((address_space(3))) void*)(&As[C][2 * 4096 + dstE]), 16, 0, 0);       \
    __builtin_amdgcn_global_load_lds(                                           \
        (__attribute__((address_space(1))) void*)(aS + 3 * 64 * (long)K2 + (long)(KT) * 64), \
        (__attribute__((address_space(3))) void*)(&As[C][3 * 4096 + dstE]), 16, 0, 0);       \
  } while (0)

// B half (tile KT, k-half KK) -> half-ring buf C (2 loads: 128 rows each)
#define STAGE_B(C, KT, KK)                                                      \
  do {                                                                          \
    __builtin_amdgcn_global_load_lds(                                           \
        (__attribute__((address_space(1))) void*)(bS + 0 * 128 * (long)K2 + (long)(KT) * 64 + (KK) * 32), \
        (__attribute__((address_space(3))) void*)(&Bs[C][0 * 4096 + dstE]), 16, 0, 0);                    \
    __builtin_amdgcn_global_load_lds(                                           \
        (__attribute__((address_space(1))) void*)(bS + 1 * 128 * (long)K2 + (long)(KT) * 64 + (KK) * 32), \
        (__attribute__((address_space(3))) void*)(&Bs[C][1 * 4096 + dstE]), 16, 0, 0);                    \
  } while (0)

// fragment reads (swizzled, conflict-free: A verified r3+, B verified r7/r8)
#define LDA(BUF, KX, MI) (*(const bf16x8*)(&As[BUF][(aAddr ^ ((KX) * 32)) + (MI) * 1024]))
#define LDB(BUF, NI)     (*(const bf16x8*)(&Bs[BUF][bAddr + (NI) * 512]))

#define MM32(A0, A1, A2, A3, A4, A5, A6, A7, B0, B1, B2, B3)                     \
  acc[0][0] = __builtin_amdgcn_mfma_f32_16x16x32_bf16(A0, B0, acc[0][0], 0,0,0); \
  acc[0][1] = __builtin_amdgcn_mfma_f32_16x16x32_bf16(A0, B1, acc[0][1], 0,0,0); \
  acc[0][2] = __builtin_amdgcn_mfma_f32_16x16x32_bf16(A0, B2, acc[0][2], 0,0,0); \
  acc[0][3] = __builtin_amdgcn_mfma_f32_16x16x32_bf16(A0, B3, acc[0][3], 0,0,0); \
  acc[1][0] = __builtin_amdgcn_mfma_f32_16x16x32_bf16(A1, B0, acc[1][0], 0,0,0); \
  acc[1][1] = __builtin_amdgcn_mfma_f32_16x16x32_bf16(A1, B1, acc[1][1], 0,0,0); \
  acc[1][2] = __builtin_amdgcn_mfma_f32_16x16x32_bf16(A1, B2, acc[1][2], 0,0,0); \
  acc[1][3] = __builtin_amdgcn_mfma_f32_16x16x32_bf16(A1, B3, acc[1][3], 0,0,0); \
  acc[2][0] = __builtin_amdgcn_mfma_f32_16x16x32_bf16(A2, B0, acc[2][0], 0,0,0); \
  acc[2][1] = __builtin_amdgcn_mfma_f32_16x16x32_bf16(A2, B1, acc[2][1], 0,0,0); \
  acc[2][2] = __builtin_amdgcn_mfma_f32_16x16x32_bf16(A2, B2, acc[2][2], 0,0,0); \
  acc[2][3] = __builtin_amdgcn_mfma_f32_16x16x32_bf16(A2, B3, acc[2][3], 0,0,0); \
  acc[3][0] = __builtin_amdgcn_mfma_f32_16x16x32_bf16(A3, B0, acc[3][0], 0,0,0); \
  acc[3][1] = __builtin_amdgcn_mfma_f32_16x16x32_bf16(A3, B1, acc[3][1], 0,0,0); \
  acc[3][2] = __builtin_amdgcn_mfma_f32_16x16x32_bf16(A3, B2, acc[3][2], 0,0,0); \
  acc[3][3] = __builtin_amdgcn_mfma_f32_16x16x32_bf16(A3, B3, acc[3][3], 0,0,0); \
  acc[4][0] = __builtin_amdgcn_mfma_f32_16x16x32_bf16(A4, B0, acc[4][0], 0,0,0); \
  acc[4][1] = __builtin_amdgcn_mfma_f32_16x16x32_bf16(A4, B1, acc[4][1], 0,0,0); \
  acc[4][2] = __builtin_amdgcn_mfma_f32_16x16x32_bf16(A4, B2, acc[4][2], 0,0,0); \
  acc[4][3] = __builtin_amdgcn_mfma_f32_16x16x32_bf16(A4, B3, acc[4][3], 0,0,0); \
  acc[5][0] = __builtin_amdgcn_mfma_f32_16x16x32_bf16(A5, B0, acc[5][0], 0,0,0); \
  acc[5][1] = __builtin_amdgcn_mfma_f32_16x16x32_bf16(A5, B1, acc[5][1], 0,0,0); \
  acc[5][2] = __builtin_amdgcn_mfma_f32_16x16x32_bf16(A5, B2, acc[5][2], 0,0,0); \
  acc[5][3] = __builtin_amdgcn_mfma_f32_16x16x32_bf16(A5, B3, acc[5][3], 0,0,0); \
  acc[6][0] = __builtin_amdgcn_mfma_f32_16x16x32_bf16(A6, B0, acc[6][0], 0,0,0); \
  acc[6][1] = __builtin_amdgcn_mfma_f32_16x16x32_bf16(A6, B1, acc[6][1], 0,0,0); \
  acc[6][2] = __builtin_amdgcn_mfma_f32_16x16x32_bf16(A6, B2, acc[6][2], 0,0,0); \
  acc[6][3] = __builtin_amdgcn_mfma_f32_16x16x32_bf16(A6, B3, acc[6][3], 0,0,0); \
  acc[7][0] = __builtin_amdgcn_mfma_f32_16x16x32_bf16(A7, B0, acc[7][0], 0,0,0); \
  acc[7][1] = __builtin_amdgcn_mfma_f32_16x16x32_bf16(A7, B1, acc[7][1], 0,0,0); \
  acc[7][2] = __builtin_amdgcn_mfma_f32_16x16x32_bf16(A7, B2, acc[7][2], 0,0,0); \
  acc[7][3] = __builtin_amdgcn_mfma_f32_16x16x32_bf16(A7, B3, acc[7][3], 0,0,0);

// One K-tile U. kk0: MFMA(aP,bP) || prefetch aQ<-A(U,kk1), bQ<-B half h+1 ||
// stage B(U+1,h1)->BS0, A(U+2)->AST.  kk1: MFMA(aQ,bQ) || prefetch
// aP<-A(U+1,kk0), bP<-B half h+2 || stage B(U+2,h0)->BS1.
#define TILE(AC, AN, AST, P1, P2, BS0, BS1, U, STGA, SB0_, SB1_, W0, W1, PRE)  \
  { /* kk0 */                                                                  \
    if (SB0_) STAGE_B(BS0, (U) + 1, 1);                                        \
    if (STGA) STAGE_A(AST, (U) + 2);                                           \
    aQ0 = LDA(AC, 1, 0); aQ1 = LDA(AC, 1, 1);                                  \
    aQ2 = LDA(AC, 1, 2); aQ3 = LDA(AC, 1, 3);                                  \
    aQ4 = LDA(AC, 1, 4); aQ5 = LDA(AC, 1, 5);                                  \
    aQ6 = LDA(AC, 1, 6); aQ7 = LDA(AC, 1, 7);                                  \
    bQ0 = LDB(P1, 0); bQ1 = LDB(P1, 1); bQ2 = LDB(P1, 2); bQ3 = LDB(P1, 3);    \
    MM32(aP0, aP1, aP2, aP3, aP4, aP5, aP6, aP7, bP0, bP1, bP2, bP3)           \
    SB(); W0(); SB(); BAR();                                                   \
  }                                                                            \
  { /* kk1 */                                                                  \
    if (SB1_) STAGE_B(BS1, (U) + 2, 0);                                        \
    if (PRE) {                                                                 \
      aP0 = LDA(AN, 0, 0); aP1 = LDA(AN, 0, 1);                                \
      aP2 = LDA(AN, 0, 2); aP3 = LDA(AN, 0, 3);                                \
      aP4 = LDA(AN, 0, 4); aP5 = LDA(AN, 0, 5);                                \
      aP6 = LDA(AN, 0, 6); aP7 = LDA(AN, 0, 7);                                \
      bP0 = LDB(P2, 0); bP1 = LDB(P2, 1); bP2 = LDB(P2, 2); bP3 = LDB(P2, 3);  \
    }                                                                          \
    MM32(aQ0, aQ1, aQ2, aQ3, aQ4, aQ5, aQ6, aQ7, bQ0, bQ1, bQ2, bQ3)          \
    SB(); W1(); SB(); BAR();                                                   \
  }

__global__ __launch_bounds__(512, 2) void gemm256(const unsigned short* __restrict__ A,
                                                  const unsigned short* __restrict__ W,
                                                  const float* __restrict__ cn,
                                                  float* __restrict__ out) {
  // A: ring-3 [3][256 rows][64 k], phys 16B-slot = logical ^ (row&7)       (96KB)
  // B: half-ring-3 [3][256 rows][32 k], phys slot = (logical + (row>>1))&3 (48KB)
  __shared__ __attribute__((aligned(16))) unsigned short As[3][16384];
  __shared__ __attribute__((aligned(16))) unsigned short Bs[3][8192];

  const int tid  = threadIdx.x;
  const int lane = tid & 63;
  const int wave = tid >> 6;
  const int wr = wave >> 2;              // 0..1 -> 128-row half of M
  const int wc = wave & 3;               // 0..3 -> 64-row slice of N

  // XCD-aware block swizzle: xcd owns 4 m-panels x 8 n-tiles
  const int bid = blockIdx.x;
  const int xcd = bid & 7, idx = bid >> 3;
  const long rowBase = (long)(xcd * 4 + (idx >> 3)) * 256;
  const long colBase = (long)(idx & 7) * 256;

  // A staging: rows (tid>>3)+{0,64,128,192}; phys slot tid&7 <- logical (tid&7)^(row&7)
  const int sr = tid >> 3;
  const int sl = (tid & 7) ^ (sr & 7);
  const unsigned short* aS = A + (rowBase + sr) * (long)K2 + sl * 8;
  // B staging: rows (tid>>2)+{0,128}; phys slot tid&3 <- logical ((tid&3)-(row>>1))&3
  const int br = tid >> 2;
  const int bl = ((tid & 3) - (tid >> 3)) & 3;
  const unsigned short* bS = W + (colBase + br) * (long)K2 + bl * 8;
  const int dstE = tid * 8;

  // fragment read bases
  const int l15 = lane & 15, l7 = lane & 7, q = lane >> 4;
  const int aAddr = (wr * 128 + l15) * 64 + ((q ^ l7) * 8);        // kk0; kk1 = ^32
  const int bAddr = (wc * 64 + l15) * 32 + (((q + (l15 >> 1)) & 3) * 8);

  f32x4 acc[8][4];
#pragma unroll
  for (int i = 0; i < 8; ++i)
#pragma unroll
    for (int j = 0; j < 4; ++j) acc[i][j] = (f32x4){0.f, 0.f, 0.f, 0.f};

  bf16x8 aP0, aP1, aP2, aP3, aP4, aP5, aP6, aP7;
  bf16x8 aQ0, aQ1, aQ2, aQ3, aQ4, aQ5, aQ6, aQ7;
  bf16x8 bP0, bP1, bP2, bP3, bQ0, bQ1, bQ2, bQ3;

  // prologue: A(0)->0, Bh0->0, Bh1->1, A(1)->1, Bh2->2  (14 loads)
  STAGE_A(0, 0);
  STAGE_B(0, 0, 0);
  STAGE_B(1, 0, 1);
  STAGE_A(1, 1);
  STAGE_B(2, 1, 0);
  VM6(); SB(); BAR();   // A0,Bh0,Bh1 landed; A1,Bh2 in flight
  // preload phase-0 fragments
  aP0 = LDA(0, 0, 0); aP1 = LDA(0, 0, 1); aP2 = LDA(0, 0, 2); aP3 = LDA(0, 0, 3);
  aP4 = LDA(0, 0, 4); aP5 = LDA(0, 0, 5); aP6 = LDA(0, 0, 6); aP7 = LDA(0, 0, 7);
  bP0 = LDB(0, 0); bP1 = LDB(0, 1); bP2 = LDB(0, 2); bP3 = LDB(0, 3);

  // tiles 0..29: period 3  (B buf for half h = h%3; A buf for tile t = t%3)
#pragma unroll 1
  for (int u = 0; u < 30; u += 3) {
    TILE(0, 1, 2, 1, 2, 0, 1, u + 0, 1, 1, 1, VM6, VM6, 1);
    TILE(1, 2, 0, 0, 1, 2, 0, u + 1, 1, 1, 1, VM6, VM6, 1);
    TILE(2, 0, 1, 2, 0, 1, 2, u + 2, 1, 1, 1, VM6, VM6, 1);
  }
  // tail: tile 30 (stage only B(31,k1)), tile 31 (no stages, no final prefetch)
  TILE(0, 1, 2, 1, 2, 0, 1, 30, 0, 1, 0, VM2, VM0, 1);
  TILE(1, 2, 0, 0, 1, 2, 0, 31, 0, 0, 0, NOW, NOW, 0);

  // epilogue: C/D layout col=lane&15, row=(lane>>4)*4+j (m89-verified)
  const int crow = (lane >> 4) * 4;
  const int ccol = lane & 15;
#pragma unroll
  for (int ni = 0; ni < 4; ++ni) {
    const long col = colBase + wc * 64 + ni * 16 + ccol;
    const float c = cn[col];
#pragma unroll
    for (int mi = 0; mi < 8; ++mi) {
      const long row = rowBase + wr * 128 + mi * 16 + crow;
      float* o = out + row * C_SZ + col;
#pragma unroll
      for (int j = 0; j < 4; ++j) o[(long)j * C_SZ] = acc[mi][ni][j] + c;
    }
  }
}

extern "C" void kernel_launch(void* const* d_in, const int* in_sizes, int n_in,
                              void* d_out, int out_size, void* d_ws, size_t ws_size,
                              hipStream_t stream) {
  const float* x       = (const float*)d_in[0];
  const float* centers = (const float*)d_in[1];
  const float* sigma   = (const float*)d_in[2];
  float* out = (float*)d_out;

  unsigned short* Aop = (unsigned short*)d_ws;            // 8192*2048 bf16
  unsigned short* Wop = Aop + (long)B_SZ * K2;            // 2048*2048 bf16
  float* cnp = (float*)(Wop + (long)C_SZ * K2);           // 2048 f32

  build_a<<<B_SZ * D_SZ / 8 / 256, 256, 0, stream>>>(x, Aop);
  prep_w<<<C_SZ, 128, 0, stream>>>(centers, sigma,
                                   out, out + (size_t)C_SZ * D_SZ, Wop, cnp);

  float* out2 = out + (size_t)2 * C_SZ * D_SZ;
  gemm256<<<256, 512, 0, stream>>>(Aop, Wop, cnp, out2);
}